// Round 10
// baseline (25.597 us; speedup 1.0000x reference)
//
#include <hip/hip_runtime.h>

// Aggregation: out[b,c,oh,ow] = sum_{i,j in 0..2} xpad[b,c,oh+i,ow+j] * w[b, c%16, i*3+j, oh*64+ow]
// B=8, C=256, H=W=OH=OW=64, WC=16, G=16, K=3, PAD=1, STRIDE=1, DIL=1.
//
// R9: NO LDS, NO barrier. Per-thread: one pixel-quad (row, ow0..ow0+3), 8 channels.
// Per channel: 3 row float4 loads (vertical reuse is L1/L2-resident: block x-set = 36 KB)
// + DPP horizontal halos (R7-proven, boundary lanes auto-zeroed) + 12 FMA.
// 41 vector-mem instrs/thread vs R8b's 109 (27 gld + 18 ds_wr + 48 ds_rd + 16 st).
// Grid 1024 = 4 blocks/CU = 16 waves/CU; launch_bounds(256,4) caps VGPR at 128.
// XCD-chunked swizzle: consecutive logical blocks (same b,wc: adjacent quarters + gblk pair
// sharing weights and halo rows) land on the same XCD for L2 hits.

#define NB 8
#define NC 256
#define NH 64
#define NW 64
#define NWC 16
#define NG 16
#define GPB 8                // channels per thread
#define GSPLIT 2

typedef float f32x4 __attribute__((ext_vector_type(4)));

__device__ __forceinline__ float dpp_shr1(float v) {   // lane i <- lane i-1 (16-lane rows), boundary -> 0
    return __int_as_float(__builtin_amdgcn_update_dpp(
        0, __float_as_int(v), 0x111, 0xf, 0xf, true));
}
__device__ __forceinline__ float dpp_shl1(float v) {   // lane i <- lane i+1 (16-lane rows), boundary -> 0
    return __int_as_float(__builtin_amdgcn_update_dpp(
        0, __float_as_int(v), 0x101, 0xf, 0xf, true));
}

__global__ __launch_bounds__(256, 4) void agg_kernel(const float* __restrict__ x,
                                                     const float* __restrict__ wt,
                                                     float* __restrict__ out) {
    const int tid = threadIdx.x;
    const int l16 = tid & 15;
    const int row = tid >> 4;          // 0..15

    // XCD-chunked swizzle (bijective, 1024 % 8 == 0).
    const int hw   = blockIdx.x;
    const int bid  = (hw & 7) * 128 + (hw >> 3);
    const int q    = bid & 3;          // quarter: 16 rows
    const int gblk = (bid >> 2) & 1;   // which 8 channels
    const int wc   = (bid >> 3) & 15;
    const int b    = bid >> 7;

    const int oh  = q * 16 + row;
    const int ow0 = l16 * 4;

    // ---- weights: 9 taps x 4 cols for this pixel-quad (reused for 8 channels) ----
    float w[9][4];
    {
        const float* wp = wt + ((b * NWC + wc) * 9) * (NH * NW) + oh * NW + ow0;
#pragma unroll
        for (int idx = 0; idx < 9; ++idx) {
            float4 t = *reinterpret_cast<const float4*>(wp + idx * (NH * NW));
            w[idx][0] = t.x; w[idx][1] = t.y; w[idx][2] = t.z; w[idx][3] = t.w;
        }
    }

    const bool has_up   = (oh > 0);
    const bool has_down = (oh < NH - 1);

#pragma unroll
    for (int cc = 0; cc < GPB; ++cc) {
        const int c = (gblk * GPB + cc) * NWC + wc;
        const float* xc = x + ((b * NC + c) * NH) * NW + ow0;

        const float4 z = make_float4(0.f, 0.f, 0.f, 0.f);
        float4 r[3];
        r[0] = has_up   ? *reinterpret_cast<const float4*>(xc + (oh - 1) * NW) : z;
        r[1] =            *reinterpret_cast<const float4*>(xc + oh * NW);
        r[2] = has_down ? *reinterpret_cast<const float4*>(xc + (oh + 1) * NW) : z;

        float acc[4] = {0.f, 0.f, 0.f, 0.f};
#pragma unroll
        for (int i = 0; i < 3; ++i) {
            const float4 m = r[i];
            const float e0 = dpp_shr1(m.w);   // x[ow0-1] from lane-1; 0 at l16==0
            const float e5 = dpp_shl1(m.x);   // x[ow0+4] from lane+1; 0 at l16==15
            const float e[6] = {e0, m.x, m.y, m.z, m.w, e5};
#pragma unroll
            for (int j = 0; j < 3; ++j) {
                const float* wj = w[i * 3 + j];
                acc[0] += e[0 + j] * wj[0];
                acc[1] += e[1 + j] * wj[1];
                acc[2] += e[2 + j] * wj[2];
                acc[3] += e[3 + j] * wj[3];
            }
        }

        float* op = out + (((b * NC + c) * NH + oh) * NW) + ow0;
        f32x4 o = {acc[0], acc[1], acc[2], acc[3]};
        __builtin_nontemporal_store(o, reinterpret_cast<f32x4*>(op));
    }
}

extern "C" void kernel_launch(void* const* d_in, const int* in_sizes, int n_in,
                              void* d_out, int out_size, void* d_ws, size_t ws_size,
                              hipStream_t stream) {
    const float* x  = (const float*)d_in[0];
    const float* wt = (const float*)d_in[1];
    float* out      = (float*)d_out;

    // Grid: 8 b * 16 wc * 2 gblk * 4 quarters = 1024 blocks of 256 threads = 4 blocks/CU.
    dim3 grid(NB * NWC * GSPLIT * 4);
    dim3 block(256);
    agg_kernel<<<grid, block, 0, stream>>>(x, wt, out);
}

// Round 11
// 20.939 us; speedup vs baseline: 1.2224x; 1.2224x over previous
//
#include <hip/hip_runtime.h>

// Aggregation: out[b,c,oh,ow] = sum_{i,j in 0..2} xpad[b,c,oh+i,ow+j] * w[b, c%16, i*3+j, oh*64+ow]
// B=8, C=256, H=W=OH=OW=64, WC=16, G=16, K=3, PAD=1, STRIDE=1, DIL=1.
//
// R10: DMA double-buffered staging. Block = (b, wc, 16-row quarter); each (row,l16) pixel
// owned by ONE thread computing all 16 channels (weight read exactly once).
// x staged via __builtin_amdgcn_global_load_lds width=16 (no VGPR round trip, no ds_writes).
// Two 36864-B LDS halves (8 channels each): stage(buf0) -> sync -> issue DMA(buf1) ->
// compute(buf0) -> sync(drains vmcnt) -> compute(buf1). Half1's HBM latency hides under
// compute0. LDS total 73728 B -> 2 blocks/CU; grid 512 = exactly 2/CU, no tail.
// Stage map is linear: f4 index f = tid + k*256 -> LDS byte f*16, exactly the DMA's
// wave-uniform-base + lane*16 pattern. OOB halo rows read a zero-init __device__ array
// (branchless address select, all lanes always issue).
// Halos via DPP lane shuffles (boundary lanes auto-zeroed). Nontemporal stores.

#define NB 8
#define NC 256
#define NH 64
#define NW 64
#define NWC 16
#define NG 16
#define STRIP 16
#define LCHR 18                 // 16 rows + 2 halo
#define LROW 64
#define LCHF (LCHR * LROW)      // 1152 floats per channel
#define HALF_FLOATS (8 * LCHF)  // 9216 floats = 36864 B per half

typedef float f32x4 __attribute__((ext_vector_type(4)));

__device__ float g_zero16[16];   // zero-initialized, never written: DMA source for pad rows

__device__ __forceinline__ float dpp_shr1(float v) {   // lane i <- lane i-1 (16-lane rows), boundary -> 0
    return __int_as_float(__builtin_amdgcn_update_dpp(
        0, __float_as_int(v), 0x111, 0xf, 0xf, true));
}
__device__ __forceinline__ float dpp_shl1(float v) {   // lane i <- lane i+1 (16-lane rows), boundary -> 0
    return __int_as_float(__builtin_amdgcn_update_dpp(
        0, __float_as_int(v), 0x101, 0xf, 0xf, true));
}

__device__ __forceinline__ void gld_lds16(const float* src, float* ldsDst) {
    __builtin_amdgcn_global_load_lds(
        (const __attribute__((address_space(1))) void*)src,
        (__attribute__((address_space(3))) void*)ldsDst, 16, 0, 0);
}

__global__ __launch_bounds__(256, 2) void agg_kernel(const float* __restrict__ x,
                                                     const float* __restrict__ wt,
                                                     float* __restrict__ out) {
    __shared__ float lds[2 * HALF_FLOATS];   // 73728 B

    const int tid = threadIdx.x;
    const int l16 = tid & 15;
    const int row = tid >> 4;          // 0..15

    // XCD-chunked swizzle (bijective, 512 % 8 == 0).
    const int hw  = blockIdx.x;
    const int bid = (hw & 7) * 64 + (hw >> 3);
    const int q   = bid & 3;           // 4 quarters of 16 rows
    const int wc  = (bid >> 2) & 15;
    const int b   = bid >> 6;

    const int oh  = q * STRIP + row;
    const int ow0 = l16 * 4;
    const int r0  = q * STRIP - 1;     // global row of LDS row 0
    const int wavebase = tid & 192;    // wave's first f4 slot within a k-step

    // ---- DMA staging of one 8-channel half: 2304 f4, 9 per thread, linear LDS ----
    auto stage_half = [&](int h) {
#pragma unroll
        for (int k = 0; k < 9; ++k) {
            const int f   = tid + k * 256;   // 0..2303
            const int ch  = f / 288;         // 288 f4 per channel (18 rows x 16)
            const int rem = f - ch * 288;
            const int r   = rem >> 4;        // 0..17
            const int c4  = rem & 15;
            const int gr  = r0 + r;
            const int c   = (h * 8 + ch) * NWC + wc;
            const float* src = ((unsigned)gr < (unsigned)NH)
                ? x + (((b * NC + c) * NH + gr) * NW) + c4 * 4
                : g_zero16;
            // dest: wave-uniform base; HW adds lane*16B -> float offset (wavebase+k*256+lane)*4 = f*4
            gld_lds16(src, &lds[h * HALF_FLOATS + (wavebase + k * 256) * 4]);
        }
    };

    stage_half(0);

    // ---- weights: 9 taps x 4 cols, read exactly once (overlaps the DMA) ----
    float w[9][4];
    {
        const float* wp = wt + ((b * NWC + wc) * 9) * (NH * NW) + oh * NW + ow0;
#pragma unroll
        for (int idx = 0; idx < 9; ++idx) {
            float4 t = *reinterpret_cast<const float4*>(wp + idx * (NH * NW));
            w[idx][0] = t.x; w[idx][1] = t.y; w[idx][2] = t.z; w[idx][3] = t.w;
        }
    }

    auto compute_half = [&](int h) {
#pragma unroll
        for (int ch = 0; ch < 8; ++ch) {
            const float* pch = &lds[h * HALF_FLOATS + ch * LCHF];
            float acc[4] = {0.f, 0.f, 0.f, 0.f};
#pragma unroll
            for (int i = 0; i < 3; ++i) {
                const float* p = pch + (row + i) * LROW + ow0;
                float4 m = *reinterpret_cast<const float4*>(p);
                const float e0 = dpp_shr1(m.w);   // x[ow0-1] from lane-1; 0 at l16==0
                const float e5 = dpp_shl1(m.x);   // x[ow0+4] from lane+1; 0 at l16==15
                const float e[6] = {e0, m.x, m.y, m.z, m.w, e5};
#pragma unroll
                for (int j = 0; j < 3; ++j) {
                    const float* wj = w[i * 3 + j];
                    acc[0] += e[0 + j] * wj[0];
                    acc[1] += e[1 + j] * wj[1];
                    acc[2] += e[2 + j] * wj[2];
                    acc[3] += e[3 + j] * wj[3];
                }
            }
            const int c = (h * 8 + ch) * NWC + wc;
            float* op = out + (((b * NC + c) * NH + oh) * NW) + ow0;
            f32x4 o = {acc[0], acc[1], acc[2], acc[3]};
            __builtin_nontemporal_store(o, reinterpret_cast<f32x4*>(op));
        }
    };

    __syncthreads();      // drains vmcnt: buf0 (and weights) ready

    stage_half(1);        // DMA into buf1 overlaps compute of buf0

    compute_half(0);

    __syncthreads();      // drains vmcnt: buf1 ready

    compute_half(1);
}

extern "C" void kernel_launch(void* const* d_in, const int* in_sizes, int n_in,
                              void* d_out, int out_size, void* d_ws, size_t ws_size,
                              hipStream_t stream) {
    const float* x  = (const float*)d_in[0];
    const float* wt = (const float*)d_in[1];
    float* out      = (float*)d_out;

    // Grid: 8 b * 16 wc * 4 quarters = 512 blocks of 256 threads = exactly 2 blocks/CU.
    dim3 grid(NB * NWC * 4);
    dim3 block(256);
    agg_kernel<<<grid, block, 0, stream>>>(x, wt, out);
}